// Round 12
// baseline (194.257 us; speedup 1.0000x reference)
//
#include <hip/hip_runtime.h>
#include <stdint.h>

#define BATCH 2
#define NSEQ 4096
#define DM 256
#define NHEAD 8
#define DH 32
#define SCALE 0.17677669529663687f    // 1/sqrt(32)

// Q is pre-scaled by SCALE*log2(e) in proj so fattn can use exp2 directly.
#if __has_builtin(__builtin_amdgcn_exp2f)
#define EXP2W(x) __builtin_amdgcn_exp2f(x)
#else
#define EXP2W(x) __expf((x) * 0.69314718055994530942f)
#endif
#define QPRE (SCALE * 1.44269504088896340736f)

typedef unsigned short ushort_t;
typedef __attribute__((ext_vector_type(8))) short short8;   // 8 bf16
typedef __attribute__((ext_vector_type(4))) float float4v;  // MFMA C/D

__device__ __forceinline__ ushort_t f2bf(float f) {
    union { float f; uint32_t i; } x; x.f = f;
    uint32_t i = x.i;
    i += ((i >> 16) & 1u) + 0x7fffu;   // RNE
    return (ushort_t)(i >> 16);
}
__device__ __forceinline__ uint32_t rne16(float f) {
    const uint32_t i = __float_as_uint(f);
    return i + 0x7fffu + ((i >> 16) & 1u);
}
// pack bf16(a) | bf16(b)<<16  (RNE).  HW single-instr path on gfx950.
#if __has_builtin(__builtin_amdgcn_cvt_pk_bf16_f32)
typedef __bf16 bf16x2_t __attribute__((ext_vector_type(2)));
__device__ __forceinline__ uint32_t pk2(float a, float b) {
    union { bf16x2_t v; uint32_t u; } c;
    c.v = __builtin_amdgcn_cvt_pk_bf16_f32(a, b);
    return c.u;
}
#else
__device__ __forceinline__ uint32_t pk2(float a, float b) {
    return __builtin_amdgcn_perm(rne16(b), rne16(a), 0x07060302u);
}
#endif

// ---------------------------------------------------------------------------
// MFMA projection.  Block = 32 rows x 256 cols, 4 waves.  grid (256, 3).
// Q,K -> [bh][n][dh] bf16 (Q pre-scaled by QPRE).
// V -> transposed [bh][dh][n'] with keys PERMUTED per 32-chunk:
// position quad*8 + kt*4 + r  <->  true key kt*16 + quad*4 + r
// (makes fattn's S^T C-layout == PV A-fragment layout, no LDS transform).
// ---------------------------------------------------------------------------
#define RST 264   // LDS row stride (ushorts)
__global__ __launch_bounds__(256) void proj_kernel(
    const float* __restrict__ x_q, const float* __restrict__ x_kv,
    const float* __restrict__ Wq, const float* __restrict__ bq,
    const float* __restrict__ Wk, const float* __restrict__ bk,
    const float* __restrict__ Wv, const float* __restrict__ bv,
    ushort_t* __restrict__ Qh, ushort_t* __restrict__ Kh,
    ushort_t* __restrict__ Vt)
{
    const int mat = blockIdx.y;                 // 0=Q 1=K 2=V
    const int n0  = blockIdx.x * 32;
    const float* x    = (mat == 0) ? x_q : x_kv;
    const float* W    = (mat == 0) ? Wq : (mat == 1) ? Wk : Wv;
    const float* bias = (mat == 0) ? bq : (mat == 1) ? bk : bv;

    __shared__ __align__(16) ushort_t xls[32 * RST];
    const int t = threadIdx.x;

    {
        const int r  = t >> 3;
        const int c0 = (t & 7) * 32;
        const float* src = x + (size_t)(n0 + r) * DM + c0;
        uint32_t d[16];
        #pragma unroll
        for (int i = 0; i < 8; i++) {
            float4 v = *(const float4*)(src + i * 4);
            d[i * 2]     = pk2(v.x, v.y);
            d[i * 2 + 1] = pk2(v.z, v.w);
        }
        uint32_t* dst = (uint32_t*)&xls[r * RST + c0];
        #pragma unroll
        for (int i = 0; i < 4; i++)
            *(uint4*)(dst + i * 4) = *(const uint4*)&d[i * 4];
    }
    __syncthreads();

    const int w    = t >> 6;
    const int l    = t & 63;
    const int lm   = l & 15;
    const int quad = l >> 4;
    const int j0   = w * 64;

    float4v acc[2][4];
    #pragma unroll
    for (int rt = 0; rt < 2; rt++)
        #pragma unroll
        for (int jt = 0; jt < 4; jt++)
            acc[rt][jt] = (float4v){0.f, 0.f, 0.f, 0.f};

    for (int kc = 0; kc < DM / 32; kc++) {
        short8 af[2];
        #pragma unroll
        for (int rt = 0; rt < 2; rt++)
            af[rt] = *(const short8*)&xls[(rt * 16 + lm) * RST + kc * 32 + quad * 8];
        #pragma unroll
        for (int jt = 0; jt < 4; jt++) {
            const float* wp = W + (size_t)(j0 + jt * 16 + lm) * DM + kc * 32 + quad * 8;
            float4 w0 = *(const float4*)wp;
            float4 w1 = *(const float4*)(wp + 4);
            uint32_t bd[4] = { pk2(w0.x, w0.y), pk2(w0.z, w0.w),
                               pk2(w1.x, w1.y), pk2(w1.z, w1.w) };
            short8 bf = *(const short8*)bd;
            acc[0][jt] = __builtin_amdgcn_mfma_f32_16x16x32_bf16(af[0], bf, acc[0][jt], 0, 0, 0);
            acc[1][jt] = __builtin_amdgcn_mfma_f32_16x16x32_bf16(af[1], bf, acc[1][jt], 0, 0, 0);
        }
    }

    const int bb = n0 >> 12;
    const int cn = n0 & (NSEQ - 1);
    #pragma unroll
    for (int jt = 0; jt < 4; jt++) {
        const int j  = j0 + jt * 16 + lm;
        const int h  = j >> 5, dd = j & 31;
        const int bh = bb * NHEAD + h;
        const float bj = bias[j];
        #pragma unroll
        for (int rt = 0; rt < 2; rt++) {
            if (mat == 2) {
                union { ushort_t u[4]; uint2 v; } pk;
                #pragma unroll
                for (int r = 0; r < 4; r++) pk.u[r] = f2bf(acc[rt][jt][r] + bj);
                *(uint2*)&Vt[((size_t)bh * DH + dd) * NSEQ + cn + quad * 8 + rt * 4] = pk.v;
            } else if (mat == 0) {
                const int nn = cn + rt * 16 + quad * 4;
                #pragma unroll
                for (int r = 0; r < 4; r++)
                    Qh[((size_t)bh * NSEQ + nn + r) * DH + dd] =
                        f2bf((acc[rt][jt][r] + bj) * QPRE);
            } else {
                const int nn = cn + rt * 16 + quad * 4;
                #pragma unroll
                for (int r = 0; r < 4; r++)
                    Kh[((size_t)bh * NSEQ + nn + r) * DH + dd] = f2bf(acc[rt][jt][r] + bj);
            }
        }
    }
}

// ---------------------------------------------------------------------------
// Flash attention, K-split x4.  Block = 4 waves on the SAME 32 q rows; wave
// wv owns keys [wv*1024, wv*1024+1024).  Unnormalized partials (no max shift
// -> additive combine) merged through LDS at the end.  grid = 2048.
// XCD swizzle: bh = (blk&7) + 8*((blk>>3)&1) pins each head to one XCD L2.
// ---------------------------------------------------------------------------
__global__ __launch_bounds__(256) void fattn_kernel(
    const ushort_t* __restrict__ Qh, const ushort_t* __restrict__ Kh,
    const ushort_t* __restrict__ Vt, float* __restrict__ out)
{
    const int blk  = blockIdx.x;
    const int xcd  = blk & 7;
    const int idx  = blk >> 3;                  // 0..255
    const int bh   = xcd + 8 * (idx & 1);
    const int qb   = idx >> 1;                  // 0..127
    const int q0   = qb * 32;
    const int b    = bh >> 3, h = bh & 7;

    const int wv   = threadIdx.x >> 6;
    const int l    = threadIdx.x & 63;
    const int lm   = l & 15;
    const int quad = l >> 4;
    const int kbase = wv * 1024;

    const ushort_t* Qb = Qh + (size_t)bh * NSEQ * DH;
    const ushort_t* Kb = Kh + (size_t)bh * NSEQ * DH;
    const ushort_t* Vb = Vt + (size_t)bh * DH * NSEQ;

    short8 qf[2];
    #pragma unroll
    for (int qt = 0; qt < 2; qt++)
        qf[qt] = *(const short8*)(Qb + (size_t)(q0 + qt * 16 + lm) * DH + quad * 8);

    short8 ones;
    #pragma unroll
    for (int i = 0; i < 8; i++) ones[i] = (short)0x3F80;   // bf16 1.0

    float4v accO[2][2], accL[2];
    #pragma unroll
    for (int qt = 0; qt < 2; qt++) {
        accO[qt][0] = (float4v){0.f, 0.f, 0.f, 0.f};
        accO[qt][1] = (float4v){0.f, 0.f, 0.f, 0.f};
        accL[qt]    = (float4v){0.f, 0.f, 0.f, 0.f};
    }
    const float4v zero = {0.f, 0.f, 0.f, 0.f};

#define KLD(k, off) (*(const short8*)(Kb + (size_t)((k) + (off) + lm) * DH + quad * 8))
#define VLD(k, half) (*(const short8*)(Vb + (size_t)((half) + lm) * NSEQ + (k) + quad * 8))

    short8 kf0 = KLD(kbase, 0), kf1 = KLD(kbase, 16);
    short8 vf0 = VLD(kbase, 0), vf1 = VLD(kbase, 16);

    for (int kk = 0; kk < 1024; kk += 32) {
        const int kn = kbase + ((kk + 32) & 1023);
        short8 nk0 = KLD(kn, 0), nk1 = KLD(kn, 16);
        short8 nv0 = VLD(kn, 0), nv1 = VLD(kn, 16);

        #pragma unroll
        for (int qt = 0; qt < 2; qt++) {
            float4v s0 = __builtin_amdgcn_mfma_f32_16x16x32_bf16(kf0, qf[qt], zero, 0, 0, 0);
            float4v s1 = __builtin_amdgcn_mfma_f32_16x16x32_bf16(kf1, qf[qt], zero, 0, 0, 0);
            float p0[4], p1[4];
            #pragma unroll
            for (int r = 0; r < 4; r++) {
                p0[r] = EXP2W(s0[r]);
                p1[r] = EXP2W(s1[r]);
            }
            uint32_t pd[4] = { pk2(p0[0], p0[1]), pk2(p0[2], p0[3]),
                               pk2(p1[0], p1[1]), pk2(p1[2], p1[3]) };
            short8 pf = *(const short8*)pd;
            accO[qt][0] = __builtin_amdgcn_mfma_f32_16x16x32_bf16(pf, vf0, accO[qt][0], 0, 0, 0);
            accO[qt][1] = __builtin_amdgcn_mfma_f32_16x16x32_bf16(pf, vf1, accO[qt][1], 0, 0, 0);
            accL[qt]    = __builtin_amdgcn_mfma_f32_16x16x32_bf16(pf, ones, accL[qt], 0, 0, 0);
        }

        kf0 = nk0; kf1 = nk1; vf0 = nv0; vf1 = nv1;
    }
#undef KLD
#undef VLD

    // ---- combine the 4 key-quarters through LDS -------------------------
    __shared__ __align__(16) float OB[4][32][36];   // pad 36: 16B-aligned rows
    __shared__ float LB[4][32];

    #pragma unroll
    for (int qt = 0; qt < 2; qt++)
        #pragma unroll
        for (int r = 0; r < 4; r++) {
            const int ql = qt * 16 + quad * 4 + r;
            OB[wv][ql][lm]      = accO[qt][0][r];
            OB[wv][ql][16 + lm] = accO[qt][1][r];
            if (lm == 0) LB[wv][ql] = accL[qt][r];
        }
    __syncthreads();

    {
        const int t  = threadIdx.x;
        const int ql = t >> 3;
        const int d0 = (t & 7) * 4;
        float4 o0 = *(const float4*)&OB[0][ql][d0];
        float4 o1 = *(const float4*)&OB[1][ql][d0];
        float4 o2 = *(const float4*)&OB[2][ql][d0];
        float4 o3 = *(const float4*)&OB[3][ql][d0];
        const float L = LB[0][ql] + LB[1][ql] + LB[2][ql] + LB[3][ql];
        const float inv = 1.0f / L;
        float4 res;
        res.x = (o0.x + o1.x + o2.x + o3.x) * inv;
        res.y = (o0.y + o1.y + o2.y + o3.y) * inv;
        res.z = (o0.z + o1.z + o2.z + o3.z) * inv;
        res.w = (o0.w + o1.w + o2.w + o3.w) * inv;
        *(float4*)&out[((size_t)b * NSEQ + q0 + ql) * DM + h * DH + d0] = res;
    }
}

// ---------------------------------------------------------------------------
extern "C" void kernel_launch(void* const* d_in, const int* in_sizes, int n_in,
                              void* d_out, int out_size, void* d_ws, size_t ws_size,
                              hipStream_t stream)
{
    const float* x_q  = (const float*)d_in[0];
    const float* x_kv = (const float*)d_in[1];
    const float* Wq   = (const float*)d_in[2];
    const float* bq   = (const float*)d_in[3];
    const float* Wk   = (const float*)d_in[4];
    const float* bk   = (const float*)d_in[5];
    const float* Wv   = (const float*)d_in[6];
    const float* bv   = (const float*)d_in[7];
    float* out = (float*)d_out;

    const size_t per = (size_t)BATCH * NHEAD * NSEQ * DH;  // 2M elems
    ushort_t* Qh = (ushort_t*)d_ws;
    ushort_t* Kh = Qh + per;
    ushort_t* Vt = Kh + per;

    dim3 pgrid(BATCH * NSEQ / 32, 3);
    proj_kernel<<<pgrid, 256, 0, stream>>>(x_q, x_kv, Wq, bq, Wk, bk, Wv, bv,
                                           Qh, Kh, Vt);

    fattn_kernel<<<2048, 256, 0, stream>>>(Qh, Kh, Vt, out);
}

// Round 14
// 186.148 us; speedup vs baseline: 1.0436x; 1.0436x over previous
//
#include <hip/hip_runtime.h>
#include <stdint.h>

#define BATCH 2
#define NSEQ 4096
#define DM 256
#define NHEAD 8
#define DH 32
#define SCALE 0.17677669529663687f    // 1/sqrt(32)
#define QPRE (SCALE * 1.44269504088896340736f)   // fold softmax scale+log2e into Wq/bq

typedef unsigned short ushort_t;
typedef __attribute__((ext_vector_type(8))) short short8;   // 8 bf16
typedef __attribute__((ext_vector_type(4))) float float4v;  // MFMA C/D

__device__ __forceinline__ ushort_t f2bf(float f) {
    union { float f; uint32_t i; } x; x.f = f;
    uint32_t i = x.i;
    i += ((i >> 16) & 1u) + 0x7fffu;   // RNE
    return (ushort_t)(i >> 16);
}
__device__ __forceinline__ uint32_t rne16(float f) {
    const uint32_t i = __float_as_uint(f);
    return i + 0x7fffu + ((i >> 16) & 1u);
}
#if __has_builtin(__builtin_amdgcn_cvt_pk_bf16_f32)
typedef __bf16 bf16x2_t __attribute__((ext_vector_type(2)));
__device__ __forceinline__ uint32_t pk2(float a, float b) {
    union { bf16x2_t v; uint32_t u; } c;
    c.v = __builtin_amdgcn_cvt_pk_bf16_f32(a, b);
    return c.u;
}
#else
__device__ __forceinline__ uint32_t pk2(float a, float b) {
    return __builtin_amdgcn_perm(rne16(b), rne16(a), 0x07060302u);
}
#endif

// Schraudolph fast 2^x: bits = 2^23*(x + 126.9563) -> v_fma + v_cvt, full rate.
// Sawtooth +-3% in frac(x); the constant part cancels in softmax ratio and the
// varying part averages over ~10^3 effective keys -> ~1e-3 output error.
__device__ __forceinline__ float fexp2(float x) {
    const float f = __builtin_fmaf(x, 8388608.0f, 1064986823.0f);
    return __uint_as_float((uint32_t)f);
}

// ---------------------------------------------------------------------------
// Pack W (fp32 -> bf16) once; Wq pre-scaled by QPRE.  Wp in d_out scratch
// (fattn rewrites every out element later, so this is safe).  grid 96x256.
// ---------------------------------------------------------------------------
__global__ __launch_bounds__(256) void packw_kernel(
    const float* __restrict__ Wq, const float* __restrict__ Wk,
    const float* __restrict__ Wv, ushort_t* __restrict__ Wp)
{
    const int mat = blockIdx.x >> 5;            // 32 blocks per mat
    const int off = (((blockIdx.x & 31) << 8) + threadIdx.x) * 8;
    const float* W = (mat == 0) ? Wq : (mat == 1) ? Wk : Wv;
    const float s  = (mat == 0) ? QPRE : 1.0f;
    float4 a = *(const float4*)(W + off);
    float4 b = *(const float4*)(W + off + 4);
    uint32_t d[4] = { pk2(a.x * s, a.y * s), pk2(a.z * s, a.w * s),
                      pk2(b.x * s, b.y * s), pk2(b.z * s, b.w * s) };
    *(uint4*)(Wp + (size_t)mat * (DM * DM) + off) = *(const uint4*)d;
}

// ---------------------------------------------------------------------------
// MFMA projection.  Block = 32 rows x 256 cols, 4 waves.  grid (256, 3).
// W loaded pre-packed (short8, no VALU).  Q/K use SWAPPED operands
// (A=W, B=x -> C row=j, col=n) so epilogue stores 4 consecutive dd as uint2.
// V keeps A=x (row=n) for its transposed/permuted store.
// Wq/Wp already carries QPRE; ONLY the bias needs the extra scale here
// (R13 bug: scaling the whole sum applied QPRE twice).
// ---------------------------------------------------------------------------
#define RST 264   // LDS row stride (ushorts)
__global__ __launch_bounds__(256) void proj_kernel(
    const float* __restrict__ x_q, const float* __restrict__ x_kv,
    const ushort_t* __restrict__ Wp,
    const float* __restrict__ bq, const float* __restrict__ bk,
    const float* __restrict__ bv,
    ushort_t* __restrict__ Qh, ushort_t* __restrict__ Kh,
    ushort_t* __restrict__ Vt)
{
    const int mat = blockIdx.y;                 // 0=Q 1=K 2=V
    const int n0  = blockIdx.x * 32;
    const float* x    = (mat == 0) ? x_q : x_kv;
    const ushort_t* W = Wp + (size_t)mat * (DM * DM);
    const float* bias = (mat == 0) ? bq : (mat == 1) ? bk : bv;
    const float bscale = (mat == 0) ? QPRE : 1.0f;   // applied to BIAS ONLY

    __shared__ __align__(16) ushort_t xls[32 * RST];
    const int t = threadIdx.x;

    {   // stage 32x256 x rows as bf16 (RNE)
        const int r  = t >> 3;
        const int c0 = (t & 7) * 32;
        const float* src = x + (size_t)(n0 + r) * DM + c0;
        uint32_t d[16];
        #pragma unroll
        for (int i = 0; i < 8; i++) {
            float4 v = *(const float4*)(src + i * 4);
            d[i * 2]     = pk2(v.x, v.y);
            d[i * 2 + 1] = pk2(v.z, v.w);
        }
        uint32_t* dst = (uint32_t*)&xls[r * RST + c0];
        #pragma unroll
        for (int i = 0; i < 4; i++)
            *(uint4*)(dst + i * 4) = *(const uint4*)&d[i * 4];
    }
    __syncthreads();

    const int w    = t >> 6;
    const int l    = t & 63;
    const int lm   = l & 15;
    const int quad = l >> 4;
    const int j0   = w * 64;

    float4v acc[2][4];
    #pragma unroll
    for (int rt = 0; rt < 2; rt++)
        #pragma unroll
        for (int jt = 0; jt < 4; jt++)
            acc[rt][jt] = (float4v){0.f, 0.f, 0.f, 0.f};

    for (int kc = 0; kc < DM / 32; kc++) {
        short8 af[2];
        #pragma unroll
        for (int rt = 0; rt < 2; rt++)
            af[rt] = *(const short8*)&xls[(rt * 16 + lm) * RST + kc * 32 + quad * 8];
        #pragma unroll
        for (int jt = 0; jt < 4; jt++) {
            short8 bf = *(const short8*)(W + (size_t)(j0 + jt * 16 + lm) * DM
                                           + kc * 32 + quad * 8);
            if (mat == 2) {   // V: C row = n
                acc[0][jt] = __builtin_amdgcn_mfma_f32_16x16x32_bf16(af[0], bf, acc[0][jt], 0, 0, 0);
                acc[1][jt] = __builtin_amdgcn_mfma_f32_16x16x32_bf16(af[1], bf, acc[1][jt], 0, 0, 0);
            } else {          // Q/K: C row = j (swapped operands)
                acc[0][jt] = __builtin_amdgcn_mfma_f32_16x16x32_bf16(bf, af[0], acc[0][jt], 0, 0, 0);
                acc[1][jt] = __builtin_amdgcn_mfma_f32_16x16x32_bf16(bf, af[1], acc[1][jt], 0, 0, 0);
            }
        }
    }

    const int bb = n0 >> 12;
    const int cn = n0 & (NSEQ - 1);
    if (mat == 2) {
        // V: C row = n-offset = rt*16 + quad*4 + r, col j = j0+jt*16+lm.
        // permuted transposed store: key rt*16+quad*4+r -> pos quad*8+rt*4+r
        #pragma unroll
        for (int jt = 0; jt < 4; jt++) {
            const int j  = j0 + jt * 16 + lm;
            const int h  = j >> 5, dd = j & 31;
            const int bh = bb * NHEAD + h;
            const float bj = bias[j];
            #pragma unroll
            for (int rt = 0; rt < 2; rt++) {
                union { ushort_t u[4]; uint2 v; } pk;
                #pragma unroll
                for (int r = 0; r < 4; r++) pk.u[r] = f2bf(acc[rt][jt][r] + bj);
                *(uint2*)&Vt[((size_t)bh * DH + dd) * NSEQ + cn + quad * 8 + rt * 4] = pk.v;
            }
        }
    } else {
        // Q/K: C row = j-offset = jt*16 + quad*4 + r, col = n-offset = rt*16+lm
        ushort_t* dst = (mat == 0) ? Qh : Kh;
        #pragma unroll
        for (int jt = 0; jt < 4; jt++) {
            const int jb = j0 + jt * 16 + quad * 4;   // 4 consecutive j
            const int h  = jb >> 5, dd0 = jb & 31;
            const int bh = bb * NHEAD + h;
            float4 b4 = *(const float4*)(bias + jb);
            #pragma unroll
            for (int rt = 0; rt < 2; rt++) {
                const int n = cn + rt * 16 + lm;
                union { ushort_t u[4]; uint2 v; } pk;
                pk.u[0] = f2bf(acc[rt][jt][0] + b4.x * bscale);
                pk.u[1] = f2bf(acc[rt][jt][1] + b4.y * bscale);
                pk.u[2] = f2bf(acc[rt][jt][2] + b4.z * bscale);
                pk.u[3] = f2bf(acc[rt][jt][3] + b4.w * bscale);
                *(uint2*)&dst[((size_t)bh * NSEQ + n) * DH + dd0] = pk.v;
            }
        }
    }
}

// ---------------------------------------------------------------------------
// Flash attention, K-split x4, register-only P, fast-exp2.
// Block = 4 waves on the SAME 32 q rows; wave wv owns a 1024-key quarter.
// Additive combine (no max shift) through LDS at the end.  grid = 2048.
// XCD swizzle: bh = (blk&7) + 8*((blk>>3)&1).
// ---------------------------------------------------------------------------
__global__ __launch_bounds__(256) void fattn_kernel(
    const ushort_t* __restrict__ Qh, const ushort_t* __restrict__ Kh,
    const ushort_t* __restrict__ Vt, float* __restrict__ out)
{
    const int blk  = blockIdx.x;
    const int xcd  = blk & 7;
    const int idx  = blk >> 3;
    const int bh   = xcd + 8 * (idx & 1);
    const int qb   = idx >> 1;
    const int q0   = qb * 32;
    const int b    = bh >> 3, h = bh & 7;

    const int wv   = threadIdx.x >> 6;
    const int l    = threadIdx.x & 63;
    const int lm   = l & 15;
    const int quad = l >> 4;
    const int kbase = wv * 1024;

    const ushort_t* Qb = Qh + (size_t)bh * NSEQ * DH;
    const ushort_t* Kb = Kh + (size_t)bh * NSEQ * DH;
    const ushort_t* Vb = Vt + (size_t)bh * DH * NSEQ;

    short8 qf[2];
    #pragma unroll
    for (int qt = 0; qt < 2; qt++)
        qf[qt] = *(const short8*)(Qb + (size_t)(q0 + qt * 16 + lm) * DH + quad * 8);

    short8 ones;
    #pragma unroll
    for (int i = 0; i < 8; i++) ones[i] = (short)0x3F80;   // bf16 1.0

    float4v accO[2][2], accL[2];
    #pragma unroll
    for (int qt = 0; qt < 2; qt++) {
        accO[qt][0] = (float4v){0.f, 0.f, 0.f, 0.f};
        accO[qt][1] = (float4v){0.f, 0.f, 0.f, 0.f};
        accL[qt]    = (float4v){0.f, 0.f, 0.f, 0.f};
    }
    const float4v zero = {0.f, 0.f, 0.f, 0.f};

#define KLD(k, off) (*(const short8*)(Kb + (size_t)((k) + (off) + lm) * DH + quad * 8))
#define VLD(k, half) (*(const short8*)(Vb + (size_t)((half) + lm) * NSEQ + (k) + quad * 8))

    short8 kf0 = KLD(kbase, 0), kf1 = KLD(kbase, 16);
    short8 vf0 = VLD(kbase, 0), vf1 = VLD(kbase, 16);

    for (int kk = 0; kk < 1024; kk += 32) {
        const int kn = kbase + ((kk + 32) & 1023);
        short8 nk0 = KLD(kn, 0), nk1 = KLD(kn, 16);
        short8 nv0 = VLD(kn, 0), nv1 = VLD(kn, 16);

        #pragma unroll
        for (int qt = 0; qt < 2; qt++) {
            float4v s0 = __builtin_amdgcn_mfma_f32_16x16x32_bf16(kf0, qf[qt], zero, 0, 0, 0);
            float4v s1 = __builtin_amdgcn_mfma_f32_16x16x32_bf16(kf1, qf[qt], zero, 0, 0, 0);
            float p0[4], p1[4];
            #pragma unroll
            for (int r = 0; r < 4; r++) {
                p0[r] = fexp2(s0[r]);
                p1[r] = fexp2(s1[r]);
            }
            uint32_t pd[4] = { pk2(p0[0], p0[1]), pk2(p0[2], p0[3]),
                               pk2(p1[0], p1[1]), pk2(p1[2], p1[3]) };
            short8 pf = *(const short8*)pd;
            accO[qt][0] = __builtin_amdgcn_mfma_f32_16x16x32_bf16(pf, vf0, accO[qt][0], 0, 0, 0);
            accO[qt][1] = __builtin_amdgcn_mfma_f32_16x16x32_bf16(pf, vf1, accO[qt][1], 0, 0, 0);
            accL[qt]    = __builtin_amdgcn_mfma_f32_16x16x32_bf16(pf, ones, accL[qt], 0, 0, 0);
        }

        kf0 = nk0; kf1 = nk1; vf0 = nv0; vf1 = nv1;
    }
#undef KLD
#undef VLD

    // ---- combine the 4 key-quarters through LDS -------------------------
    __shared__ __align__(16) float OB[4][32][36];
    __shared__ float LB[4][32];

    #pragma unroll
    for (int qt = 0; qt < 2; qt++)
        #pragma unroll
        for (int r = 0; r < 4; r++) {
            const int ql = qt * 16 + quad * 4 + r;
            OB[wv][ql][lm]      = accO[qt][0][r];
            OB[wv][ql][16 + lm] = accO[qt][1][r];
            if (lm == 0) LB[wv][ql] = accL[qt][r];
        }
    __syncthreads();

    {
        const int tt = threadIdx.x;
        const int ql = tt >> 3;
        const int d0 = (tt & 7) * 4;
        float4 o0 = *(const float4*)&OB[0][ql][d0];
        float4 o1 = *(const float4*)&OB[1][ql][d0];
        float4 o2 = *(const float4*)&OB[2][ql][d0];
        float4 o3 = *(const float4*)&OB[3][ql][d0];
        const float L = LB[0][ql] + LB[1][ql] + LB[2][ql] + LB[3][ql];
        const float inv = 1.0f / L;
        float4 res;
        res.x = (o0.x + o1.x + o2.x + o3.x) * inv;
        res.y = (o0.y + o1.y + o2.y + o3.y) * inv;
        res.z = (o0.z + o1.z + o2.z + o3.z) * inv;
        res.w = (o0.w + o1.w + o2.w + o3.w) * inv;
        *(float4*)&out[((size_t)b * NSEQ + q0 + ql) * DM + h * DH + d0] = res;
    }
}

// ---------------------------------------------------------------------------
extern "C" void kernel_launch(void* const* d_in, const int* in_sizes, int n_in,
                              void* d_out, int out_size, void* d_ws, size_t ws_size,
                              hipStream_t stream)
{
    const float* x_q  = (const float*)d_in[0];
    const float* x_kv = (const float*)d_in[1];
    const float* Wq   = (const float*)d_in[2];
    const float* bq   = (const float*)d_in[3];
    const float* Wk   = (const float*)d_in[4];
    const float* bk   = (const float*)d_in[5];
    const float* Wv   = (const float*)d_in[6];
    const float* bv   = (const float*)d_in[7];
    float* out = (float*)d_out;

    const size_t per = (size_t)BATCH * NHEAD * NSEQ * DH;  // 2M elems
    ushort_t* Qh = (ushort_t*)d_ws;
    ushort_t* Kh = Qh + per;
    ushort_t* Vt = Kh + per;
    // W bf16 scratch lives at the START of d_out: fattn later overwrites
    // every out element, so this is safe (proj reads it before fattn runs).
    ushort_t* Wp = (ushort_t*)d_out;

    packw_kernel<<<96, 256, 0, stream>>>(Wq, Wk, Wv, Wp);

    dim3 pgrid(BATCH * NSEQ / 32, 3);
    proj_kernel<<<pgrid, 256, 0, stream>>>(x_q, x_kv, Wp, bq, bk, bv,
                                           Qh, Kh, Vt);

    fattn_kernel<<<2048, 256, 0, stream>>>(Qh, Kh, Vt, out);
}

// Round 15
// 185.316 us; speedup vs baseline: 1.0482x; 1.0045x over previous
//
#include <hip/hip_runtime.h>
#include <stdint.h>

#define BATCH 2
#define NSEQ 4096
#define DM 256
#define NHEAD 8
#define DH 32
#define SCALE 0.17677669529663687f    // 1/sqrt(32)
#define QPRE (SCALE * 1.44269504088896340736f)   // softmax scale+log2e folded into Wq/bq

#if __has_builtin(__builtin_amdgcn_exp2f)
#define EXP2W(x) __builtin_amdgcn_exp2f(x)
#else
#define EXP2W(x) exp2f(x)
#endif

typedef unsigned short ushort_t;
typedef __attribute__((ext_vector_type(8))) short short8;   // 8 bf16
typedef __attribute__((ext_vector_type(4))) float float4v;  // MFMA C/D

__device__ __forceinline__ ushort_t f2bf(float f) {
    union { float f; uint32_t i; } x; x.f = f;
    uint32_t i = x.i;
    i += ((i >> 16) & 1u) + 0x7fffu;   // RNE
    return (ushort_t)(i >> 16);
}
__device__ __forceinline__ uint32_t rne16(float f) {
    const uint32_t i = __float_as_uint(f);
    return i + 0x7fffu + ((i >> 16) & 1u);
}
#if __has_builtin(__builtin_amdgcn_cvt_pk_bf16_f32)
typedef __bf16 bf16x2_t __attribute__((ext_vector_type(2)));
__device__ __forceinline__ uint32_t pk2(float a, float b) {
    union { bf16x2_t v; uint32_t u; } c;
    c.v = __builtin_amdgcn_cvt_pk_bf16_f32(a, b);
    return c.u;
}
#else
__device__ __forceinline__ uint32_t pk2(float a, float b) {
    return __builtin_amdgcn_perm(rne16(b), rne16(a), 0x07060302u);
}
#endif

// async global->LDS, 16B per lane (dest = wave-uniform base + lane*16)
__device__ __forceinline__ void load_lds_16B(const void* g, void* lds) {
    __builtin_amdgcn_global_load_lds(
        (const __attribute__((address_space(1))) void*)g,
        (__attribute__((address_space(3))) void*)lds, 16, 0, 0);
}

// ---------------------------------------------------------------------------
// Pack W (fp32 -> bf16) once; Wq pre-scaled by QPRE.  Wp in d_out scratch.
// ---------------------------------------------------------------------------
__global__ __launch_bounds__(256) void packw_kernel(
    const float* __restrict__ Wq, const float* __restrict__ Wk,
    const float* __restrict__ Wv, ushort_t* __restrict__ Wp)
{
    const int mat = blockIdx.x >> 5;
    const int off = (((blockIdx.x & 31) << 8) + threadIdx.x) * 8;
    const float* W = (mat == 0) ? Wq : (mat == 1) ? Wk : Wv;
    const float s  = (mat == 0) ? QPRE : 1.0f;
    float4 a = *(const float4*)(W + off);
    float4 b = *(const float4*)(W + off + 4);
    uint32_t d[4] = { pk2(a.x * s, a.y * s), pk2(a.z * s, a.w * s),
                      pk2(b.x * s, b.y * s), pk2(b.z * s, b.w * s) };
    *(uint4*)(Wp + (size_t)mat * (DM * DM) + off) = *(const uint4*)d;
}

// ---------------------------------------------------------------------------
// MFMA projection (unchanged from R14).  Q,K -> [bh][n][dh]; V -> transposed
// [bh][dh][n'] with keys permuted per 32-chunk (pos quad*8+kt*4+r <-> key
// kt*16+quad*4+r) so fattn's S^T C-layout == PV A-fragment layout.
// ---------------------------------------------------------------------------
#define RST 264
__global__ __launch_bounds__(256) void proj_kernel(
    const float* __restrict__ x_q, const float* __restrict__ x_kv,
    const ushort_t* __restrict__ Wp,
    const float* __restrict__ bq, const float* __restrict__ bk,
    const float* __restrict__ bv,
    ushort_t* __restrict__ Qh, ushort_t* __restrict__ Kh,
    ushort_t* __restrict__ Vt)
{
    const int mat = blockIdx.y;
    const int n0  = blockIdx.x * 32;
    const float* x    = (mat == 0) ? x_q : x_kv;
    const ushort_t* W = Wp + (size_t)mat * (DM * DM);
    const float* bias = (mat == 0) ? bq : (mat == 1) ? bk : bv;
    const float bscale = (mat == 0) ? QPRE : 1.0f;   // bias only (Wp carries QPRE)

    __shared__ __align__(16) ushort_t xls[32 * RST];
    const int t = threadIdx.x;
    {
        const int r  = t >> 3;
        const int c0 = (t & 7) * 32;
        const float* src = x + (size_t)(n0 + r) * DM + c0;
        uint32_t d[16];
        #pragma unroll
        for (int i = 0; i < 8; i++) {
            float4 v = *(const float4*)(src + i * 4);
            d[i * 2]     = pk2(v.x, v.y);
            d[i * 2 + 1] = pk2(v.z, v.w);
        }
        uint32_t* dst = (uint32_t*)&xls[r * RST + c0];
        #pragma unroll
        for (int i = 0; i < 4; i++)
            *(uint4*)(dst + i * 4) = *(const uint4*)&d[i * 4];
    }
    __syncthreads();

    const int w    = t >> 6;
    const int l    = t & 63;
    const int lm   = l & 15;
    const int quad = l >> 4;
    const int j0   = w * 64;

    float4v acc[2][4];
    #pragma unroll
    for (int rt = 0; rt < 2; rt++)
        #pragma unroll
        for (int jt = 0; jt < 4; jt++)
            acc[rt][jt] = (float4v){0.f, 0.f, 0.f, 0.f};

    for (int kc = 0; kc < DM / 32; kc++) {
        short8 af[2];
        #pragma unroll
        for (int rt = 0; rt < 2; rt++)
            af[rt] = *(const short8*)&xls[(rt * 16 + lm) * RST + kc * 32 + quad * 8];
        #pragma unroll
        for (int jt = 0; jt < 4; jt++) {
            short8 bf = *(const short8*)(W + (size_t)(j0 + jt * 16 + lm) * DM
                                           + kc * 32 + quad * 8);
            if (mat == 2) {
                acc[0][jt] = __builtin_amdgcn_mfma_f32_16x16x32_bf16(af[0], bf, acc[0][jt], 0, 0, 0);
                acc[1][jt] = __builtin_amdgcn_mfma_f32_16x16x32_bf16(af[1], bf, acc[1][jt], 0, 0, 0);
            } else {
                acc[0][jt] = __builtin_amdgcn_mfma_f32_16x16x32_bf16(bf, af[0], acc[0][jt], 0, 0, 0);
                acc[1][jt] = __builtin_amdgcn_mfma_f32_16x16x32_bf16(bf, af[1], acc[1][jt], 0, 0, 0);
            }
        }
    }

    const int bb = n0 >> 12;
    const int cn = n0 & (NSEQ - 1);
    if (mat == 2) {
        #pragma unroll
        for (int jt = 0; jt < 4; jt++) {
            const int j  = j0 + jt * 16 + lm;
            const int h  = j >> 5, dd = j & 31;
            const int bh = bb * NHEAD + h;
            const float bj = bias[j];
            #pragma unroll
            for (int rt = 0; rt < 2; rt++) {
                union { ushort_t u[4]; uint2 v; } pk;
                #pragma unroll
                for (int r = 0; r < 4; r++) pk.u[r] = f2bf(acc[rt][jt][r] + bj);
                *(uint2*)&Vt[((size_t)bh * DH + dd) * NSEQ + cn + quad * 8 + rt * 4] = pk.v;
            }
        }
    } else {
        ushort_t* dst = (mat == 0) ? Qh : Kh;
        #pragma unroll
        for (int jt = 0; jt < 4; jt++) {
            const int jb = j0 + jt * 16 + quad * 4;
            const int h  = jb >> 5, dd0 = jb & 31;
            const int bh = bb * NHEAD + h;
            float4 b4 = *(const float4*)(bias + jb);
            #pragma unroll
            for (int rt = 0; rt < 2; rt++) {
                const int n = cn + rt * 16 + lm;
                union { ushort_t u[4]; uint2 v; } pk;
                pk.u[0] = f2bf(acc[rt][jt][0] + b4.x * bscale);
                pk.u[1] = f2bf(acc[rt][jt][1] + b4.y * bscale);
                pk.u[2] = f2bf(acc[rt][jt][2] + b4.z * bscale);
                pk.u[3] = f2bf(acc[rt][jt][3] + b4.w * bscale);
                *(uint2*)&dst[((size_t)bh * NSEQ + n) * DH + dd0] = pk.v;
            }
        }
    }
}

// ---------------------------------------------------------------------------
// Flash attention, LDS-staged K/V shared by all 4 waves (txns / 4).
// Block = 4 waves x 64 q = 256 q on one (b,h); each wave walks ALL 4096 keys.
// Per 32-key iter: stage next 4KB tile (K 2KB + V 2KB) via global_load_lds
// (1 instr per wave), 1 barrier, fragments via 4 ds_read_b128/wave.
// grid 256 = 1 block/CU; XCD-pinned (2 heads per XCD -> K/V fits 4MB L2).
// ---------------------------------------------------------------------------
#define QT 4
__global__ __launch_bounds__(256) void fattn_kernel(
    const ushort_t* __restrict__ Qh, const ushort_t* __restrict__ Kh,
    const ushort_t* __restrict__ Vt, float* __restrict__ out)
{
    const int blk  = blockIdx.x;
    const int xcd  = blk & 7;
    const int jj   = blk >> 3;                  // 0..31
    const int bh   = xcd * 2 + (jj & 1);
    const int qblk = jj >> 1;                   // 0..15
    const int b    = bh >> 3, h = bh & 7;

    const int w    = threadIdx.x >> 6;
    const int l    = threadIdx.x & 63;
    const int lm   = l & 15;
    const int quad = l >> 4;
    const int q0   = qblk * 256 + w * 64;

    // [buf][ K tile 1024 ushorts | V tile 1024 ushorts ]
    __shared__ __align__(16) ushort_t tiles[2][2048];

    const ushort_t* Qb = Qh + (size_t)bh * NSEQ * DH;
    const ushort_t* Kb = Kh + (size_t)bh * NSEQ * DH;
    const ushort_t* Vb = Vt + (size_t)bh * DH * NSEQ;

    // staging source for this wave's 1KB quarter (waves 0,1: K; 2,3: V)
    const ushort_t* gsrc;
    int gadv;
    if (w < 2) { gsrc = Kb + (size_t)(w * 16 + (l >> 2)) * DH + (l & 3) * 8;  gadv = 32 * DH; }
    else       { gsrc = Vb + (size_t)((w - 2) * 16 + (l >> 2)) * NSEQ + (l & 3) * 8; gadv = 32; }

    short8 qf[QT];
    #pragma unroll
    for (int qt = 0; qt < QT; qt++)
        qf[qt] = *(const short8*)(Qb + (size_t)(q0 + qt * 16 + lm) * DH + quad * 8);

    short8 ones;
    #pragma unroll
    for (int i = 0; i < 8; i++) ones[i] = (short)0x3F80;   // bf16 1.0

    float4v accO[QT][2], accL[QT];
    #pragma unroll
    for (int qt = 0; qt < QT; qt++) {
        accO[qt][0] = (float4v){0.f, 0.f, 0.f, 0.f};
        accO[qt][1] = (float4v){0.f, 0.f, 0.f, 0.f};
        accL[qt]    = (float4v){0.f, 0.f, 0.f, 0.f};
    }
    const float4v zero = {0.f, 0.f, 0.f, 0.f};

    // prologue: stage tile 0 into buf 0
    load_lds_16B(gsrc, &tiles[0][w * 512]);
    gsrc += gadv;

    for (int it = 0; it < NSEQ / 32; it++) {
        __syncthreads();              // drains vmcnt -> tile(it) resident
        if (it < NSEQ / 32 - 1) {     // stage tile(it+1) into the other buf
            load_lds_16B(gsrc, &tiles[(it + 1) & 1][w * 512]);
            gsrc += gadv;
        }

        const ushort_t* Kt = &tiles[it & 1][0];
        const ushort_t* Vl = &tiles[it & 1][1024];
        short8 kf0 = *(const short8*)&Kt[lm * 32 + quad * 8];
        short8 kf1 = *(const short8*)&Kt[512 + lm * 32 + quad * 8];
        short8 vf0 = *(const short8*)&Vl[lm * 32 + quad * 8];
        short8 vf1 = *(const short8*)&Vl[512 + lm * 32 + quad * 8];

        #pragma unroll
        for (int qt = 0; qt < QT; qt++) {
            float4v s0 = __builtin_amdgcn_mfma_f32_16x16x32_bf16(kf0, qf[qt], zero, 0, 0, 0);
            float4v s1 = __builtin_amdgcn_mfma_f32_16x16x32_bf16(kf1, qf[qt], zero, 0, 0, 0);
            float p0[4], p1[4];
            #pragma unroll
            for (int r = 0; r < 4; r++) {
                p0[r] = EXP2W(s0[r]);
                p1[r] = EXP2W(s1[r]);
            }
            uint32_t pd[4] = { pk2(p0[0], p0[1]), pk2(p0[2], p0[3]),
                               pk2(p1[0], p1[1]), pk2(p1[2], p1[3]) };
            short8 pf = *(const short8*)pd;
            accO[qt][0] = __builtin_amdgcn_mfma_f32_16x16x32_bf16(pf, vf0, accO[qt][0], 0, 0, 0);
            accO[qt][1] = __builtin_amdgcn_mfma_f32_16x16x32_bf16(pf, vf1, accO[qt][1], 0, 0, 0);
            accL[qt]    = __builtin_amdgcn_mfma_f32_16x16x32_bf16(pf, ones, accL[qt], 0, 0, 0);
        }
    }

    // epilogue: accL[qt][r] = L[q0 + qt*16 + quad*4 + r] (same rows as accO)
    #pragma unroll
    for (int qt = 0; qt < QT; qt++)
        #pragma unroll
        for (int r = 0; r < 4; r++) {
            const float inv = 1.0f / accL[qt][r];
            const int q = q0 + qt * 16 + quad * 4 + r;
            float* orow = out + ((size_t)b * NSEQ + q) * DM + h * DH;
            orow[lm]      = accO[qt][0][r] * inv;
            orow[16 + lm] = accO[qt][1][r] * inv;
        }
}

// ---------------------------------------------------------------------------
extern "C" void kernel_launch(void* const* d_in, const int* in_sizes, int n_in,
                              void* d_out, int out_size, void* d_ws, size_t ws_size,
                              hipStream_t stream)
{
    const float* x_q  = (const float*)d_in[0];
    const float* x_kv = (const float*)d_in[1];
    const float* Wq   = (const float*)d_in[2];
    const float* bq   = (const float*)d_in[3];
    const float* Wk   = (const float*)d_in[4];
    const float* bk   = (const float*)d_in[5];
    const float* Wv   = (const float*)d_in[6];
    const float* bv   = (const float*)d_in[7];
    float* out = (float*)d_out;

    const size_t per = (size_t)BATCH * NHEAD * NSEQ * DH;  // 2M elems
    ushort_t* Qh = (ushort_t*)d_ws;
    ushort_t* Kh = Qh + per;
    ushort_t* Vt = Kh + per;
    ushort_t* Wp = (ushort_t*)d_out;   // scratch; fattn rewrites all of out

    packw_kernel<<<96, 256, 0, stream>>>(Wq, Wk, Wv, Wp);

    dim3 pgrid(BATCH * NSEQ / 32, 3);
    proj_kernel<<<pgrid, 256, 0, stream>>>(x_q, x_kv, Wp, bq, bk, bv,
                                           Qh, Kh, Vt);

    fattn_kernel<<<256, 256, 0, stream>>>(Qh, Kh, Vt, out);
}